// Round 7
// baseline (358.049 us; speedup 1.0000x reference)
//
#include <hip/hip_runtime.h>
#include <math.h>

// Problem constants
constexpr int D      = 1024;
constexpr int H      = 16;
constexpr int DH     = 64;
constexpr int Bb     = 2;
constexpr int T      = 2048;
constexpr int BT     = Bb * T;       // 4096
constexpr int CHUNK  = 64;
constexpr int NC     = T / CHUNK;    // 32
constexpr int LS     = 72;           // LDS row stride (shorts); R3-verified

typedef __attribute__((ext_vector_type(8))) short bf16x8;
typedef __attribute__((ext_vector_type(4))) float f32x4;

#define GLOAD_LDS16(gp, lp) \
    __builtin_amdgcn_global_load_lds((const __attribute__((address_space(1))) void*)(gp), \
                                     (__attribute__((address_space(3))) void*)(lp), 16, 0, 0)

__device__ __forceinline__ short to_bf16(float f) {
    unsigned u = __float_as_uint(f);
    unsigned r = (u + 0x7fffu + ((u >> 16) & 1u)) >> 16;
    return (short)r;
}
__device__ __forceinline__ float bf2f(short s) {
    return __uint_as_float(((unsigned)(unsigned short)s) << 16);
}

__device__ __forceinline__ float elu1(float x) {
    return x > 0.0f ? x + 1.0f : __expf(x);
}

// Lessons ledger:
//  R2: no cooperative launches (graph capture fails silently).
//  R4: no software grid SPIN barriers (agent-scope polling = cross-XCD L2
//      invalidate storm, +170 us).  One-shot device atomics are fine (gmean).
//  R5: no O(NC^2) cross-XCD re-reads (L3-speed) to save an O(NC) round-trip.
//  R7: testing "kernel boundaries cost ~8-12 us" via last-block-done merge.

// ---------------------------------------------------------------------------
// Merged prologue: blocks [0,1024): LayerNorm, 4 rows/block, one wave per row;
// [1024, 1024+1280): three weight transposes (fp32 -> bf16, [K,N] -> [N,K])
// in 64x64 tiles.  Block 0 also zeroes the 64 group-done counters.
// ---------------------------------------------------------------------------
__global__ __launch_bounds__(256) void pre_kernel(const float* __restrict__ x,
                                                  const float* __restrict__ g,
                                                  const float* __restrict__ b,
                                                  const float* __restrict__ wq,
                                                  const float* __restrict__ wg,
                                                  const float* __restrict__ wp,
                                                  short* __restrict__ ynb,
                                                  short* __restrict__ xbb,
                                                  short* __restrict__ wTcomb,
                                                  short* __restrict__ wTp,
                                                  float* __restrict__ gmean,
                                                  unsigned* __restrict__ done) {
    __shared__ short tile2[64 * 72];   // 18 KB transpose stage
    int bid = blockIdx.x;
    int tid = threadIdx.x;
    if (bid < 1024) {
        if (bid == 0 && tid < Bb * H) done[tid] = 0;
        int row  = bid * 4 + (tid >> 6);
        int lane = tid & 63;
        const float* xr = x + (size_t)row * D;
        float4 xv[4];
        float s = 0.0f;
        #pragma unroll
        for (int i = 0; i < 4; ++i) {
            xv[i] = *(const float4*)(xr + i * 256 + lane * 4);
            s += xv[i].x + xv[i].y + xv[i].z + xv[i].w;
        }
        #pragma unroll
        for (int off = 32; off > 0; off >>= 1) s += __shfl_xor(s, off, 64);
        float mu = s * (1.0f / D);
        float vs = 0.0f;
        #pragma unroll
        for (int i = 0; i < 4; ++i) {
            float d0 = xv[i].x - mu, d1 = xv[i].y - mu;
            float d2 = xv[i].z - mu, d3 = xv[i].w - mu;
            vs += d0 * d0 + d1 * d1 + d2 * d2 + d3 * d3;
        }
        #pragma unroll
        for (int off = 32; off > 0; off >>= 1) vs += __shfl_xor(vs, off, 64);
        float rstd = rsqrtf(vs * (1.0f / D) + 1e-5f);
        if (lane == 0) gmean[row] = 0.0f;
        #pragma unroll
        for (int i = 0; i < 4; ++i) {
            int cc = i * 256 + lane * 4;
            float4 gv = *(const float4*)(g + cc);
            float4 bv = *(const float4*)(b + cc);
            short4 o, xo;
            o.x = to_bf16((xv[i].x - mu) * rstd * gv.x + bv.x);
            o.y = to_bf16((xv[i].y - mu) * rstd * gv.y + bv.y);
            o.z = to_bf16((xv[i].z - mu) * rstd * gv.z + bv.z);
            o.w = to_bf16((xv[i].w - mu) * rstd * gv.w + bv.w);
            xo.x = to_bf16(xv[i].x); xo.y = to_bf16(xv[i].y);
            xo.z = to_bf16(xv[i].z); xo.w = to_bf16(xv[i].w);
            *(short4*)(ynb + (size_t)row * D + cc) = o;
            *(short4*)(xbb + (size_t)row * D + cc) = xo;
        }
    } else {
        int t2 = bid - 1024;                 // 0..1279
        const float* W; short* Wt; int N; int t;
        if (t2 < 768)       { W = wq; Wt = wTcomb;                       N = 3072; t = t2; }
        else if (t2 < 1024) { W = wg; Wt = wTcomb + (size_t)3072 * 1024; N = 1024; t = t2 - 768; }
        else                { W = wp; Wt = wTp;                          N = 1024; t = t2 - 1024; }
        int ntn = N >> 6;                    // 64-col tiles
        int nb = (t % ntn) * 64, kb = (t / ntn) * 64;

        int k  = tid >> 2;                   // 0..63
        int n4 = (tid & 3) * 16;             // 0,16,32,48
        const float* src = W + (size_t)(kb + k) * N + nb + n4;
        float4 f0 = *(const float4*)(src);
        float4 f1 = *(const float4*)(src + 4);
        float4 f2 = *(const float4*)(src + 8);
        float4 f3 = *(const float4*)(src + 12);
        bf16x8 h0, h1;
        h0[0] = to_bf16(f0.x); h0[1] = to_bf16(f0.y); h0[2] = to_bf16(f0.z); h0[3] = to_bf16(f0.w);
        h0[4] = to_bf16(f1.x); h0[5] = to_bf16(f1.y); h0[6] = to_bf16(f1.z); h0[7] = to_bf16(f1.w);
        h1[0] = to_bf16(f2.x); h1[1] = to_bf16(f2.y); h1[2] = to_bf16(f2.z); h1[3] = to_bf16(f2.w);
        h1[4] = to_bf16(f3.x); h1[5] = to_bf16(f3.y); h1[6] = to_bf16(f3.z); h1[7] = to_bf16(f3.w);
        *(bf16x8*)&tile2[k * 72 + n4]     = h0;
        *(bf16x8*)&tile2[k * 72 + n4 + 8] = h1;
        __syncthreads();

        int n   = tid >> 2;                  // 0..63
        int k16 = (tid & 3) * 16;            // 0,16,32,48
        bf16x8 o0, o1;
        #pragma unroll
        for (int j = 0; j < 8; ++j) o0[j] = tile2[(k16 + j) * 72 + n];
        #pragma unroll
        for (int j = 0; j < 8; ++j) o1[j] = tile2[(k16 + 8 + j) * 72 + n];
        short* dst = Wt + (size_t)(nb + n) * 1024 + kb + k16;
        *(bf16x8*)dst       = o0;
        *(bf16x8*)(dst + 8) = o1;
    }
}

// ---------------------------------------------------------------------------
// Combined qkv+gate GEMM: 256^2 / BK=64 / 8-wave counted-vmcnt pipeline
// (unchanged from R1: 50.0 us, 0 bank conflicts).
// ---------------------------------------------------------------------------
#define SWZ(os) ((os) ^ ((((os) >> 6) & 3) << 3))
#define BARX() __builtin_amdgcn_s_barrier()
#define LGKM0() asm volatile("s_waitcnt lgkmcnt(0)" ::: "memory")
#define VMW(n) asm volatile("s_waitcnt vmcnt(" #n ")" ::: "memory")
#define MEMFENCE() asm volatile("" ::: "memory")

#define STG(Mp, rb, t, kc, isB) do {                                                       \
    short* _b = ldsbuf + ((((t) & 1)) << 15) + (((((isB) << 1) | (kc))) << 13) + wid * 1024; \
    const short* _g = (Mp) + (size_t)((rb) + wid * 32 + s_r) * 1024 + (t) * 64 + (kc) * 32 + s_c; \
    GLOAD_LDS16(_g, _b);                                                                   \
    GLOAD_LDS16(_g + (size_t)16 * 1024, _b + 512);                                         \
} while (0)

#define FRAGA(t, kc, mi) (*(const bf16x8*)(ldsbuf + (((t) & 1) << 15) + ((kc) << 13) + \
    SWZ((wm * 128 + (mi) * 16 + fr) * 32 + fk)))
#define FRAGB(t, kc, ni) (*(const bf16x8*)(ldsbuf + (((t) & 1) << 15) + ((2 + (kc)) << 13) + \
    SWZ((wn * 64 + (ni) * 16 + fr) * 32 + fk)))

#define GROUP(t, S1, S2, S3, S4, W2, W4) do {                                              \
    bf16x8 af[8], bq[4];                                                                   \
    _Pragma("unroll") for (int mi = 0; mi < 8; ++mi) af[mi] = FRAGA(t, 0, mi);             \
    bq[0] = FRAGB(t, 0, 0); bq[1] = FRAGB(t, 0, 1);                                        \
    if (S1) STG(Wt, col0, (t) + 1, 1, 1);                                                  \
    BARX(); LGKM0();                                                                       \
    __builtin_amdgcn_s_setprio(1);                                                         \
    _Pragma("unroll") for (int mi = 0; mi < 8; ++mi) {                                     \
        acc[mi][0] = __builtin_amdgcn_mfma_f32_16x16x32_bf16(af[mi], bq[0], acc[mi][0], 0, 0, 0); \
        acc[mi][1] = __builtin_amdgcn_mfma_f32_16x16x32_bf16(af[mi], bq[1], acc[mi][1], 0, 0, 0); \
    }                                                                                      \
    __builtin_amdgcn_s_setprio(0);                                                         \
    BARX();                                                                                \
    bq[2] = FRAGB(t, 0, 2); bq[3] = FRAGB(t, 0, 3);                                        \
    if (S2) STG(Ap, row0, (t) + 2, 0, 0);                                                  \
    BARX(); LGKM0();                                                                       \
    __builtin_amdgcn_s_setprio(1);                                                         \
    _Pragma("unroll") for (int mi = 0; mi < 8; ++mi) {                                     \
        acc[mi][2] = __builtin_amdgcn_mfma_f32_16x16x32_bf16(af[mi], bq[2], acc[mi][2], 0, 0, 0); \
        acc[mi][3] = __builtin_amdgcn_mfma_f32_16x16x32_bf16(af[mi], bq[3], acc[mi][3], 0, 0, 0); \
    }                                                                                      \
    __builtin_amdgcn_s_setprio(0);                                                         \
    W2; BARX();                                                                            \
    _Pragma("unroll") for (int mi = 0; mi < 8; ++mi) af[mi] = FRAGA(t, 1, mi);             \
    bq[0] = FRAGB(t, 1, 0); bq[1] = FRAGB(t, 1, 1);                                        \
    if (S3) STG(Wt, col0, (t) + 2, 0, 1);                                                  \
    BARX(); LGKM0();                                                                       \
    __builtin_amdgcn_s_setprio(1);                                                         \
    _Pragma("unroll") for (int mi = 0; mi < 8; ++mi) {                                     \
        acc[mi][0] = __builtin_amdgcn_mfma_f32_16x16x32_bf16(af[mi], bq[0], acc[mi][0], 0, 0, 0); \
        acc[mi][1] = __builtin_amdgcn_mfma_f32_16x16x32_bf16(af[mi], bq[1], acc[mi][1], 0, 0, 0); \
    }                                                                                      \
    __builtin_amdgcn_s_setprio(0);                                                         \
    BARX();                                                                                \
    bq[2] = FRAGB(t, 1, 2); bq[3] = FRAGB(t, 1, 3);                                        \
    if (S4) STG(Ap, row0, (t) + 2, 1, 0);                                                  \
    BARX(); LGKM0();                                                                       \
    __builtin_amdgcn_s_setprio(1);                                                         \
    _Pragma("unroll") for (int mi = 0; mi < 8; ++mi) {                                     \
        acc[mi][2] = __builtin_amdgcn_mfma_f32_16x16x32_bf16(af[mi], bq[2], acc[mi][2], 0, 0, 0); \
        acc[mi][3] = __builtin_amdgcn_mfma_f32_16x16x32_bf16(af[mi], bq[3], acc[mi][3], 0, 0, 0); \
    }                                                                                      \
    __builtin_amdgcn_s_setprio(0);                                                         \
    W4; BARX();                                                                            \
} while (0)

__global__ __launch_bounds__(512, 2) void gemm_fused_qkvgate(const short* __restrict__ xnb,
                                                             const short* __restrict__ xb,
                                                             const short* __restrict__ Wt,
                                                             const float* __restrict__ b_qkv,
                                                             const float* __restrict__ b_gate,
                                                             short* __restrict__ qkvb,
                                                             short* __restrict__ sigb,
                                                             float* __restrict__ gmean) {
    __shared__ short ldsbuf[2 * 32768];

    const int bid   = blockIdx.x;
    const int xcd   = bid & 7;
    const int local = bid >> 3;            // 0..31
    const int cx = xcd & 3, ry = xcd >> 2; // 4 col-slabs x 2 row-slabs
    const int bxx = cx * 4 + (local & 3);  // 0..15 col-block
    const int byy = ry * 8 + (local >> 2); // 0..15 row-block
    const int row0 = byy * 256;
    const int col0 = bxx * 256;
    const bool isg = (col0 >= 3 * D);
    const short* Ap = isg ? xb : xnb;

    const int tid  = threadIdx.x;
    const int wid  = tid >> 6;     // 0..7
    const int lane = tid & 63;
    const int wm = wid >> 2;       // 0..1  (row half)
    const int wn = wid & 3;        // 0..3  (col quarter)
    const int fr = lane & 15;
    const int fk = (lane >> 4) * 8;

    const int s_r = lane >> 2;                              // 0..15
    const int s_c = 8 * ((lane & 3) ^ ((lane >> 3) & 3));   // 0,8,16,24 permuted

    f32x4 acc[8][4] = {};

    STG(Ap, row0, 0, 0, 0); MEMFENCE();
    STG(Wt, col0, 0, 0, 1); MEMFENCE();
    STG(Ap, row0, 0, 1, 0); MEMFENCE();
    STG(Wt, col0, 0, 1, 1); MEMFENCE();
    STG(Ap, row0, 1, 0, 0); MEMFENCE();
    STG(Wt, col0, 1, 0, 1); MEMFENCE();
    STG(Ap, row0, 1, 1, 0);
    VMW(10);
    BARX();

    for (int t = 0; t < 14; ++t) GROUP(t, 1, 1, 1, 1, VMW(10), VMW(10));
    GROUP(14, 1, 0, 0, 0, VMW(8), VMW(4));
    GROUP(15, 0, 0, 0, 0, VMW(0), (void)0);

    const int ccol  = lane & 15;
    const int crow4 = (lane >> 4) * 4;
    if (!isg) {
        #pragma unroll
        for (int mi = 0; mi < 8; ++mi) {
            #pragma unroll
            for (int ni = 0; ni < 4; ++ni) {
                int col = col0 + wn * 64 + ni * 16 + ccol;
                float bv = b_qkv[col];
                #pragma unroll
                for (int r = 0; r < 4; ++r) {
                    int row = row0 + wm * 128 + mi * 16 + crow4 + r;
                    qkvb[(size_t)row * (3 * D) + col] = to_bf16(acc[mi][ni][r] + bv);
                }
            }
        }
    } else {
        #pragma unroll
        for (int mi = 0; mi < 8; ++mi) {
            #pragma unroll
            for (int r = 0; r < 4; ++r) {
                int lrow = row0 + wm * 128 + mi * 16 + crow4 + r;
                float psum = 0.0f;
                #pragma unroll
                for (int ni = 0; ni < 4; ++ni) {
                    int col = col0 + wn * 64 + ni * 16 + ccol - 3 * D;   // [0,D)
                    float v = acc[mi][ni][r] + b_gate[col];
                    float sv = 1.0f / (1.0f + __expf(-v));
                    sigb[(size_t)lrow * D + col] = to_bf16(sv);
                    psum += sv;
                }
                psum += __shfl_xor(psum, 1, 64);
                psum += __shfl_xor(psum, 2, 64);
                psum += __shfl_xor(psum, 4, 64);
                psum += __shfl_xor(psum, 8, 64);
                if (ccol == 0) atomicAdd(&gmean[lrow], psum);
            }
        }
    }
}

// ---------------------------------------------------------------------------
// Per-chunk state with INLINE gating on k, PLUS merged prefix: the last block
// of each (b,h) group (device-scope one-shot atomic, no spinning) performs the
// exclusive prefix over its group's 32 chunk states (register-pipelined,
// identical fp32 sum order -> bit-identical).  Removes the prefix kernel and
// one kernel boundary.
// ---------------------------------------------------------------------------
__global__ __launch_bounds__(256) void chunk_state_mfma(const short* __restrict__ qkvb,
                                                        const short* __restrict__ sigb,
                                                        const float* __restrict__ gmean,
                                                        float* __restrict__ Sc,
                                                        short* __restrict__ Spb,
                                                        float* __restrict__ zc,
                                                        unsigned* __restrict__ done) {
    __shared__ short Kt[DH * LS];   // [d][t] gated k
    __shared__ short Vt[DH * LS];   // [m][t]
    __shared__ int isLast;
    int idx = blockIdx.x;
    int c = idx & (NC - 1), h = (idx >> 5) & (H - 1), b = idx >> 9;
    size_t bt0 = (size_t)b * T + c * CHUNK;
    const short* kbase = qkvb + bt0 * (3 * D) + D + h * DH;
    const short* vbase = kbase + D;
    const short* sbase = sigb + bt0 * D + h * DH;
    int tid = threadIdx.x;

    #pragma unroll
    for (int l = 0; l < 2; ++l) {
        int i  = tid + l * 256;
        int t  = i >> 3;
        int d8 = (i & 7) * 8;
        float invm = 1.0f / (gmean[bt0 + t] * (1.0f / D) + 1e-5f);
        bf16x8 kv = *(const bf16x8*)(kbase + (size_t)t * (3 * D) + d8);
        bf16x8 vv = *(const bf16x8*)(vbase + (size_t)t * (3 * D) + d8);
        bf16x8 sg = *(const bf16x8*)(sbase + (size_t)t * D + d8);
        #pragma unroll
        for (int j = 0; j < 8; ++j) {
            float gn = bf2f(sg[j]) * invm;
            Kt[(d8 + j) * LS + t] = to_bf16(elu1(bf2f(kv[j]) * gn));
            Vt[(d8 + j) * LS + t] = vv[j];
        }
    }
    __syncthreads();

    const int wv = tid >> 6, lane = tid & 63;
    const int fr = lane & 15, quad = lane >> 4;
    const int fk = quad * 8, crow4 = quad * 4, ccol = lane & 15;
    const int mbase = wv * 16;

    bf16x8 af0 = *(const bf16x8*)&Vt[(mbase + fr) * LS + fk];
    bf16x8 af1 = *(const bf16x8*)&Vt[(mbase + fr) * LS + 32 + fk];

    f32x4 acc[4] = {};
    #pragma unroll
    for (int n = 0; n < 4; ++n) {
        bf16x8 bk0 = *(const bf16x8*)&Kt[(n * 16 + fr) * LS + fk];
        bf16x8 bk1 = *(const bf16x8*)&Kt[(n * 16 + fr) * LS + 32 + fk];
        acc[n] = __builtin_amdgcn_mfma_f32_16x16x32_bf16(af0, bk0, acc[n], 0, 0, 0);
        acc[n] = __builtin_amdgcn_mfma_f32_16x16x32_bf16(af1, bk1, acc[n], 0, 0, 0);
    }

    float* Sd = Sc + (size_t)idx * (DH * DH);
    #pragma unroll
    for (int n = 0; n < 4; ++n)
        #pragma unroll
        for (int r = 0; r < 4; ++r)
            Sd[(mbase + crow4 + r) * DH + n * 16 + ccol] = acc[n][r];

    // zc[d] = sum_t Kt[d][t], all threads: d = tid>>2, 16-wide t-slice per lane
    {
        int d = tid >> 2, p = tid & 3;
        bf16x8 k0 = *(const bf16x8*)&Kt[d * LS + p * 16];
        bf16x8 k1 = *(const bf16x8*)&Kt[d * LS + p * 16 + 8];
        float zs = 0.0f;
        #pragma unroll
        for (int j = 0; j < 8; ++j) zs += bf2f(k0[j]) + bf2f(k1[j]);
        zs += __shfl_xor(zs, 1, 64);
        zs += __shfl_xor(zs, 2, 64);
        if (p == 0) zc[(size_t)idx * DH + d] = zs;
    }

    // ---- last-block-done prefix (one-shot signal, NO spinning) ----
    __threadfence();                 // publish Sc/zc at device scope
    __syncthreads();                 // all threads' stores issued before signal
    if (tid == 0) {
        unsigned old = __hip_atomic_fetch_add(&done[idx >> 5], 1u,
                                              __ATOMIC_ACQ_REL, __HIP_MEMORY_SCOPE_AGENT);
        isLast = (old == NC - 1);
    }
    __syncthreads();
    if (isLast) {
        int grp = idx >> 5;          // b*H + h
        const float* Sb = Sc + (size_t)grp * NC * DH * DH;
        short* Pb = Spb + (size_t)grp * NC * DH * DH;
        #pragma unroll 1
        for (int pass = 0; pass < 16; ++pass) {
            int e = pass * 256 + tid;
            float v[NC];
            #pragma unroll
            for (int cc = 0; cc < NC; ++cc) v[cc] = Sb[(size_t)cc * (DH * DH) + e];
            float a = 0.0f;
            #pragma unroll
            for (int cc = 0; cc < NC; ++cc) {
                Pb[(size_t)cc * (DH * DH) + e] = to_bf16(a);
                a += v[cc];
            }
        }
        if (tid < DH) {
            float* zb = zc + (size_t)grp * NC * DH + tid;
            float zv[NC];
            #pragma unroll
            for (int cc = 0; cc < NC; ++cc) zv[cc] = zb[(size_t)cc * DH];
            float za = 0.0f;
            #pragma unroll
            for (int cc = 0; cc < NC; ++cc) {
                zb[(size_t)cc * DH] = za;
                za += zv[cc];
            }
        }
    }
}

// ---------------------------------------------------------------------------
// Chunk attention with INLINE gating on q,k. As aliases Ks (dead after scores).
// Reads bf16 Spb + scanned zc.  (R3-verified structure)
// ---------------------------------------------------------------------------
__global__ __launch_bounds__(256) void chunk_attn_mfma(const short* __restrict__ qkvb,
                                                       const short* __restrict__ sigb,
                                                       const float* __restrict__ gmean,
                                                       const short* __restrict__ Spb,
                                                       const float* __restrict__ zc,
                                                       short* __restrict__ attnb) {
    __shared__ short Qs[CHUNK * LS];   // [t][d] gated q
    __shared__ short Ks[CHUNK * LS];   // [s][d] gated k; reused as As[t][s]
    __shared__ short Vt[DH * LS];      // [m][s]
    __shared__ short Ss[DH * LS];      // [m][d]  (prefix state, bf16)
    __shared__ float zpL[DH];
    __shared__ float den[CHUNK];
    short* As = Ks;                    // alias: Ks dead after scores

    int idx = blockIdx.x;
    int c = idx & (NC - 1), h = (idx >> 5) & (H - 1), b = idx >> 9;
    size_t bt0 = (size_t)b * T + c * CHUNK;
    const short* qbase = qkvb + bt0 * (3 * D) + h * DH;
    const short* kbase = qbase + D;
    const short* vbase = qbase + 2 * D;
    const short* sbase = sigb + bt0 * D + h * DH;
    const short* spb = Spb + (size_t)idx * (DH * DH);
    int tid = threadIdx.x;

    #pragma unroll
    for (int l = 0; l < 2; ++l) {
        int i  = tid + l * 256;
        int t  = i >> 3;
        int d8 = (i & 7) * 8;
        float invm = 1.0f / (gmean[bt0 + t] * (1.0f / D) + 1e-5f);
        bf16x8 qv = *(const bf16x8*)(qbase + (size_t)t * (3 * D) + d8);
        bf16x8 kv = *(const bf16x8*)(kbase + (size_t)t * (3 * D) + d8);
        bf16x8 vv = *(const bf16x8*)(vbase + (size_t)t * (3 * D) + d8);
        bf16x8 sg = *(const bf16x8*)(sbase + (size_t)t * D + d8);
        bf16x8 qg, kg;
        #pragma unroll
        for (int j = 0; j < 8; ++j) {
            float gn = bf2f(sg[j]) * invm;
            qg[j] = to_bf16(elu1(bf2f(qv[j]) * gn));
            kg[j] = to_bf16(elu1(bf2f(kv[j]) * gn));
            Vt[(d8 + j) * LS + t] = vv[j];
        }
        *(bf16x8*)&Qs[t * LS + d8] = qg;
        *(bf16x8*)&Ks[t * LS + d8] = kg;
        *(bf16x8*)&Ss[t * LS + d8] = *(const bf16x8*)(spb + (size_t)i * 8);
    }
    if (tid < DH) zpL[tid] = zc[(size_t)idx * DH + tid];
    __syncthreads();

    const int wv = tid >> 6, lane = tid & 63;
    const int fr = lane & 15, quad = lane >> 4;
    const int fk = quad * 8, crow4 = quad * 4, ccol = lane & 15;
    const int tbase = wv * 16;

    bf16x8 aq0 = *(const bf16x8*)&Qs[(tbase + fr) * LS + fk];
    bf16x8 aq1 = *(const bf16x8*)&Qs[(tbase + fr) * LS + 32 + fk];

    // scores C[t][s] = q_t . k_s
    f32x4 accs[4] = {};
    #pragma unroll
    for (int n = 0; n < 4; ++n) {
        bf16x8 bk0 = *(const bf16x8*)&Ks[(n * 16 + fr) * LS + fk];
        bf16x8 bk1 = *(const bf16x8*)&Ks[(n * 16 + fr) * LS + 32 + fk];
        accs[n] = __builtin_amdgcn_mfma_f32_16x16x32_bf16(aq0, bk0, accs[n], 0, 0, 0);
        accs[n] = __builtin_amdgcn_mfma_f32_16x16x32_bf16(aq1, bk1, accs[n], 0, 0, 0);
    }
    __syncthreads();   // all Ks reads complete before As overwrites it

    float part[4] = {0.f, 0.f, 0.f, 0.f};
    #pragma unroll
    for (int n = 0; n < 4; ++n) {
        #pragma unroll
        for (int r = 0; r < 4; ++r) {
            int tt = tbase + crow4 + r;
            int ss = n * 16 + ccol;
            float v = (ss <= tt) ? accs[n][r] : 0.0f;
            part[r] += v;
            As[tt * LS + ss] = to_bf16(v);
        }
    }
    #pragma unroll
    for (int r = 0; r < 4; ++r) {
        part[r] += __shfl_xor(part[r], 1, 64);
        part[r] += __shfl_xor(part[r], 2, 64);
        part[r] += __shfl_xor(part[r], 4, 64);
        part[r] += __shfl_xor(part[r], 8, 64);
    }
    if (fr == 0) {
        #pragma unroll
        for (int r = 0; r < 4; ++r) den[tbase + crow4 + r] = part[r];
    }
    __syncthreads();

    // den[t] += q_t . zp, all threads: t = tid>>2, 16-wide d-slice per lane
    {
        int t = tid >> 2, p = tid & 3;
        bf16x8 q0 = *(const bf16x8*)&Qs[t * LS + p * 16];
        bf16x8 q1 = *(const bf16x8*)&Qs[t * LS + p * 16 + 8];
        float qz = 0.0f;
        #pragma unroll
        for (int j = 0; j < 8; ++j)
            qz += bf2f(q0[j]) * zpL[p * 16 + j] + bf2f(q1[j]) * zpL[p * 16 + 8 + j];
        qz += __shfl_xor(qz, 1, 64);
        qz += __shfl_xor(qz, 2, 64);
        if (p == 0) den[t] += qz + 1e-5f;
    }

    // out C[t][m] = Q @ Sp + A @ V
    f32x4 acco[4] = {};
    #pragma unroll
    for (int m4 = 0; m4 < 4; ++m4) {
        bf16x8 bs0 = *(const bf16x8*)&Ss[(m4 * 16 + fr) * LS + fk];
        bf16x8 bs1 = *(const bf16x8*)&Ss[(m4 * 16 + fr) * LS + 32 + fk];
        acco[m4] = __builtin_amdgcn_mfma_f32_16x16x32_bf16(aq0, bs0, acco[m4], 0, 0, 0);
        acco[m4] = __builtin_amdgcn_mfma_f32_16x16x32_bf16(aq1, bs1, acco[m4], 0, 0, 0);
    }
    bf16x8 aa0 = *(const bf16x8*)&As[(tbase + fr) * LS + fk];
    bf16x8 aa1 = *(const bf16x8*)&As[(tbase + fr) * LS + 32 + fk];
    #pragma unroll
    for (int m4 = 0; m4 < 4; ++m4) {
        bf16x8 bv0 = *(const bf16x8*)&Vt[(m4 * 16 + fr) * LS + fk];
        bf16x8 bv1 = *(const bf16x8*)&Vt[(m4 * 16 + fr) * LS + 32 + fk];
        acco[m4] = __builtin_amdgcn_mfma_f32_16x16x32_bf16(aa0, bv0, acco[m4], 0, 0, 0);
        acco[m4] = __builtin_amdgcn_mfma_f32_16x16x32_bf16(aa1, bv1, acco[m4], 0, 0, 0);
    }
    __syncthreads();

    short* obase = attnb + bt0 * D + h * DH;
    #pragma unroll
    for (int r = 0; r < 4; ++r) {
        int tt = tbase + crow4 + r;
        float rv = 1.0f / den[tt];
        #pragma unroll
        for (int m4 = 0; m4 < 4; ++m4)
            obase[(size_t)tt * D + m4 * 16 + ccol] = to_bf16(acco[m4][r] * rv);
    }
}

// ---------------------------------------------------------------------------
// Proj GEMM, BK=64 + 3-bit XOR LDS swizzle + XCD-rectangle swizzle (R6).
// ---------------------------------------------------------------------------
#define SWZ64(os) ((os) ^ ((((os) >> 6) & 7) << 3))

__global__ __launch_bounds__(256) void gemm_proj64(const short* __restrict__ A,
                                                   const short* __restrict__ Bt,
                                                   const float* __restrict__ bias,
                                                   float* __restrict__ C) {
    constexpr int BK = 64, K = 1024;
    constexpr int N = 1024;
    __shared__ short Als[64 * BK];    // 8 KB
    __shared__ short Bls[128 * BK];   // 16 KB

    const int bid   = blockIdx.x;
    const int xcd   = bid & 7;
    const int local = bid >> 3;            // 0..63
    const int cx = xcd & 3, ry = xcd >> 2; // 4 col-slabs x 2 row-slabs
    const int lx = local & 1, ly = local >> 1;
    const int bxx = cx * 2 + lx;           // 0..7 col-block
    const int byy = ry * 32 + ly;          // 0..63 row-block

    const int tid  = threadIdx.x;
    const int wave = tid >> 6;
    const int lane = tid & 63;
    const int row0 = byy * 64;
    const int col0 = bxx * 128;
    const int wn = wave * 32;

    f32x4 acc[4][2] = {};
    const int fr = lane & 15;
    const int fk = (lane >> 4) * 8;

    for (int k0 = 0; k0 < K; k0 += BK) {
        __syncthreads();
        #pragma unroll
        for (int u = 0; u < 2; ++u) {
            int slot = tid + u * 256;
            int r = slot >> 3, c8 = (slot & 7) ^ (r & 7);
            GLOAD_LDS16(A + (size_t)(row0 + r) * K + k0 + c8 * 8, &Als[slot * 8]);
        }
        #pragma unroll
        for (int u = 0; u < 4; ++u) {
            int slot = tid + u * 256;
            int r = slot >> 3, c8 = (slot & 7) ^ (r & 7);
            GLOAD_LDS16(Bt + (size_t)(col0 + r) * K + k0 + c8 * 8, &Bls[slot * 8]);
        }
        __syncthreads();

        #pragma unroll
        for (int ck = 0; ck < 2; ++ck) {
            bf16x8 af[4], bfr[2];
            #pragma unroll
            for (int i = 0; i < 4; ++i)
                af[i] = *(const bf16x8*)&Als[SWZ64((i * 16 + fr) * BK + ck * 32 + fk)];
            #pragma unroll
            for (int j = 0; j < 2; ++j)
                bfr[j] = *(const bf16x8*)&Bls[SWZ64((wn + j * 16 + fr) * BK + ck * 32 + fk)];
            #pragma unroll
            for (int mi = 0; mi < 4; ++mi)
                #pragma unroll
                for (int ni = 0; ni < 2; ++ni)
                    acc[mi][ni] = __builtin_amdgcn_mfma_f32_16x16x32_bf16(af[mi], bfr[ni], acc[mi][ni], 0, 0, 0);
        }
    }

    const int ccol  = lane & 15;
    const int crow4 = (lane >> 4) * 4;
    #pragma unroll
    for (int mi = 0; mi < 4; ++mi) {
        #pragma unroll
        for (int ni = 0; ni < 2; ++ni) {
            int col = col0 + wn + ni * 16 + ccol;
            float bv = bias[col];
            #pragma unroll
            for (int r = 0; r < 4; ++r) {
                int row = row0 + mi * 16 + crow4 + r;
                C[(size_t)row * N + col] = acc[mi][ni][r] + bv;
            }
        }
    }
}

// ---------------------------------------------------------------------------
extern "C" void kernel_launch(void* const* d_in, const int* in_sizes, int n_in,
                              void* d_out, int out_size, void* d_ws, size_t ws_size,
                              hipStream_t stream) {
    const float* x      = (const float*)d_in[0];
    const float* ln_g   = (const float*)d_in[1];
    const float* ln_b   = (const float*)d_in[2];
    const float* w_qkv  = (const float*)d_in[3];
    const float* b_qkv  = (const float*)d_in[4];
    const float* w_gate = (const float*)d_in[5];
    const float* b_gate = (const float*)d_in[6];
    const float* w_proj = (const float*)d_in[7];
    const float* b_proj = (const float*)d_in[8];
    float* out = (float*)d_out;

    short* xnb   = (short*)d_ws;                       // BT*D bf16 (8 MB)  [dead after GEMM]
    short* xb    = xnb + (size_t)BT * D;               // BT*D bf16 (8 MB)  [dead after GEMM]
    short* wTc   = xb + (size_t)BT * D;                // 4096*1024 bf16 (8 MB) [dead after GEMM]
    short* wTp   = wTc + (size_t)4096 * 1024;          // D*D bf16 (2 MB)
    short* qkvb  = wTp + (size_t)D * D;                // BT*3D bf16 (24 MB)
    short* sigb  = qkvb + (size_t)BT * 3 * D;          // BT*D bf16 (8 MB)
    short* attnb = sigb + (size_t)BT * D;              // BT*D bf16 (8 MB)
    float* zc    = (float*)(attnb + (size_t)BT * D);   // Bb*H*NC*DH fp32 (256 KB)
    float* gmean = zc + (size_t)Bb * H * NC * DH;      // BT fp32 (16 KB)
    unsigned* done = (unsigned*)(gmean + BT);          // Bb*H group-done counters
    float* Sc    = (float*)xnb;                        // Bb*H*NC*DH*DH fp32 (16 MB), aliases xnb+xb
    short* Spb   = wTc;                                // BT*D bf16 (8 MB), aliases wTc

    pre_kernel<<<1024 + 1280, 256, 0, stream>>>(x, ln_g, ln_b, w_qkv, w_gate, w_proj,
                                                xnb, xb, wTc, wTp, gmean, done);
    gemm_fused_qkvgate<<<256, 512, 0, stream>>>(
        xnb, xb, wTc, b_qkv, b_gate, qkvb, sigb, gmean);
    chunk_state_mfma<<<Bb * H * NC, 256, 0, stream>>>(qkvb, sigb, gmean, Sc, Spb, zc, done);
    chunk_attn_mfma<<<Bb * H * NC, 256, 0, stream>>>(qkvb, sigb, gmean, Spb, zc, attnb);
    gemm_proj64<<<512, 256, 0, stream>>>(attnb, wTp, b_proj, out);
}

// Round 8
// 182.160 us; speedup vs baseline: 1.9656x; 1.9656x over previous
//
#include <hip/hip_runtime.h>
#include <math.h>

// Problem constants
constexpr int D      = 1024;
constexpr int H      = 16;
constexpr int DH     = 64;
constexpr int Bb     = 2;
constexpr int T      = 2048;
constexpr int BT     = Bb * T;       // 4096
constexpr int CHUNK  = 64;
constexpr int NC     = T / CHUNK;    // 32
constexpr int LS     = 72;           // LDS row stride (shorts); R3-verified

typedef __attribute__((ext_vector_type(8))) short bf16x8;
typedef __attribute__((ext_vector_type(4))) float f32x4;

#define GLOAD_LDS16(gp, lp) \
    __builtin_amdgcn_global_load_lds((const __attribute__((address_space(1))) void*)(gp), \
                                     (__attribute__((address_space(3))) void*)(lp), 16, 0, 0)

__device__ __forceinline__ short to_bf16(float f) {
    unsigned u = __float_as_uint(f);
    unsigned r = (u + 0x7fffu + ((u >> 16) & 1u)) >> 16;
    return (short)r;
}
__device__ __forceinline__ float bf2f(short s) {
    return __uint_as_float(((unsigned)(unsigned short)s) << 16);
}

__device__ __forceinline__ float elu1(float x) {
    return x > 0.0f ? x + 1.0f : __expf(x);
}

// Lessons ledger:
//  R2: no cooperative launches (graph capture fails silently).
//  R4+R7: no per-block device-scope FENCES (__threadfence / acq-rel atomics).
//      Agent-scope release => cross-XCD L2 writeback storm: +170-200 us both
//      times.  Plain relaxed atomicAdd (gmean) is fine.  Producer->consumer
//      across blocks goes through kernel boundaries ONLY.
//  R5: no O(NC^2) cross-XCD re-reads (L3-speed) to save an O(NC) round-trip.
//  R8: transposed-scatter LDS writes at LS=72 were 16-way bank-conflicted
//      (2.03M conflict cycles/dispatch, R7 counters); fixed by XOR-swizzling
//      column-block with (d>>3)&7 (write side now uniform 2-way = free).

// ---------------------------------------------------------------------------
// Merged prologue: blocks [0,1024): LayerNorm, 4 rows/block, one wave per row;
// [1024, 1024+1280): three weight transposes (fp32 -> bf16, [K,N] -> [N,K])
// in 64x64 tiles.
// ---------------------------------------------------------------------------
__global__ __launch_bounds__(256) void pre_kernel(const float* __restrict__ x,
                                                  const float* __restrict__ g,
                                                  const float* __restrict__ b,
                                                  const float* __restrict__ wq,
                                                  const float* __restrict__ wg,
                                                  const float* __restrict__ wp,
                                                  short* __restrict__ ynb,
                                                  short* __restrict__ xbb,
                                                  short* __restrict__ wTcomb,
                                                  short* __restrict__ wTp,
                                                  float* __restrict__ gmean) {
    __shared__ short tile2[64 * 72];   // 18 KB transpose stage
    int bid = blockIdx.x;
    int tid = threadIdx.x;
    if (bid < 1024) {
        int row  = bid * 4 + (tid >> 6);
        int lane = tid & 63;
        const float* xr = x + (size_t)row * D;
        float4 xv[4];
        float s = 0.0f;
        #pragma unroll
        for (int i = 0; i < 4; ++i) {
            xv[i] = *(const float4*)(xr + i * 256 + lane * 4);
            s += xv[i].x + xv[i].y + xv[i].z + xv[i].w;
        }
        #pragma unroll
        for (int off = 32; off > 0; off >>= 1) s += __shfl_xor(s, off, 64);
        float mu = s * (1.0f / D);
        float vs = 0.0f;
        #pragma unroll
        for (int i = 0; i < 4; ++i) {
            float d0 = xv[i].x - mu, d1 = xv[i].y - mu;
            float d2 = xv[i].z - mu, d3 = xv[i].w - mu;
            vs += d0 * d0 + d1 * d1 + d2 * d2 + d3 * d3;
        }
        #pragma unroll
        for (int off = 32; off > 0; off >>= 1) vs += __shfl_xor(vs, off, 64);
        float rstd = rsqrtf(vs * (1.0f / D) + 1e-5f);
        if (lane == 0) gmean[row] = 0.0f;
        #pragma unroll
        for (int i = 0; i < 4; ++i) {
            int cc = i * 256 + lane * 4;
            float4 gv = *(const float4*)(g + cc);
            float4 bv = *(const float4*)(b + cc);
            short4 o, xo;
            o.x = to_bf16((xv[i].x - mu) * rstd * gv.x + bv.x);
            o.y = to_bf16((xv[i].y - mu) * rstd * gv.y + bv.y);
            o.z = to_bf16((xv[i].z - mu) * rstd * gv.z + bv.z);
            o.w = to_bf16((xv[i].w - mu) * rstd * gv.w + bv.w);
            xo.x = to_bf16(xv[i].x); xo.y = to_bf16(xv[i].y);
            xo.z = to_bf16(xv[i].z); xo.w = to_bf16(xv[i].w);
            *(short4*)(ynb + (size_t)row * D + cc) = o;
            *(short4*)(xbb + (size_t)row * D + cc) = xo;
        }
    } else {
        int t2 = bid - 1024;                 // 0..1279
        const float* W; short* Wt; int N; int t;
        if (t2 < 768)       { W = wq; Wt = wTcomb;                       N = 3072; t = t2; }
        else if (t2 < 1024) { W = wg; Wt = wTcomb + (size_t)3072 * 1024; N = 1024; t = t2 - 768; }
        else                { W = wp; Wt = wTp;                          N = 1024; t = t2 - 1024; }
        int ntn = N >> 6;                    // 64-col tiles
        int nb = (t % ntn) * 64, kb = (t / ntn) * 64;

        int k  = tid >> 2;                   // 0..63
        int n4 = (tid & 3) * 16;             // 0,16,32,48
        const float* src = W + (size_t)(kb + k) * N + nb + n4;
        float4 f0 = *(const float4*)(src);
        float4 f1 = *(const float4*)(src + 4);
        float4 f2 = *(const float4*)(src + 8);
        float4 f3 = *(const float4*)(src + 12);
        bf16x8 h0, h1;
        h0[0] = to_bf16(f0.x); h0[1] = to_bf16(f0.y); h0[2] = to_bf16(f0.z); h0[3] = to_bf16(f0.w);
        h0[4] = to_bf16(f1.x); h0[5] = to_bf16(f1.y); h0[6] = to_bf16(f1.z); h0[7] = to_bf16(f1.w);
        h1[0] = to_bf16(f2.x); h1[1] = to_bf16(f2.y); h1[2] = to_bf16(f2.z); h1[3] = to_bf16(f2.w);
        h1[4] = to_bf16(f3.x); h1[5] = to_bf16(f3.y); h1[6] = to_bf16(f3.z); h1[7] = to_bf16(f3.w);
        *(bf16x8*)&tile2[k * 72 + n4]     = h0;
        *(bf16x8*)&tile2[k * 72 + n4 + 8] = h1;
        __syncthreads();

        int n   = tid >> 2;                  // 0..63
        int k16 = (tid & 3) * 16;            // 0,16,32,48
        bf16x8 o0, o1;
        #pragma unroll
        for (int j = 0; j < 8; ++j) o0[j] = tile2[(k16 + j) * 72 + n];
        #pragma unroll
        for (int j = 0; j < 8; ++j) o1[j] = tile2[(k16 + 8 + j) * 72 + n];
        short* dst = Wt + (size_t)(nb + n) * 1024 + kb + k16;
        *(bf16x8*)dst       = o0;
        *(bf16x8*)(dst + 8) = o1;
    }
}

// ---------------------------------------------------------------------------
// Combined qkv+gate GEMM: 256^2 / BK=64 / 8-wave counted-vmcnt pipeline
// (unchanged from R1: 50.0 us, 0 bank conflicts).
// ---------------------------------------------------------------------------
#define SWZ(os) ((os) ^ ((((os) >> 6) & 3) << 3))
#define BARX() __builtin_amdgcn_s_barrier()
#define LGKM0() asm volatile("s_waitcnt lgkmcnt(0)" ::: "memory")
#define VMW(n) asm volatile("s_waitcnt vmcnt(" #n ")" ::: "memory")
#define MEMFENCE() asm volatile("" ::: "memory")

#define STG(Mp, rb, t, kc, isB) do {                                                       \
    short* _b = ldsbuf + ((((t) & 1)) << 15) + (((((isB) << 1) | (kc))) << 13) + wid * 1024; \
    const short* _g = (Mp) + (size_t)((rb) + wid * 32 + s_r) * 1024 + (t) * 64 + (kc) * 32 + s_c; \
    GLOAD_LDS16(_g, _b);                                                                   \
    GLOAD_LDS16(_g + (size_t)16 * 1024, _b + 512);                                         \
} while (0)

#define FRAGA(t, kc, mi) (*(const bf16x8*)(ldsbuf + (((t) & 1) << 15) + ((kc) << 13) + \
    SWZ((wm * 128 + (mi) * 16 + fr) * 32 + fk)))
#define FRAGB(t, kc, ni) (*(const bf16x8*)(ldsbuf + (((t) & 1) << 15) + ((2 + (kc)) << 13) + \
    SWZ((wn * 64 + (ni) * 16 + fr) * 32 + fk)))

#define GROUP(t, S1, S2, S3, S4, W2, W4) do {                                              \
    bf16x8 af[8], bq[4];                                                                   \
    _Pragma("unroll") for (int mi = 0; mi < 8; ++mi) af[mi] = FRAGA(t, 0, mi);             \
    bq[0] = FRAGB(t, 0, 0); bq[1] = FRAGB(t, 0, 1);                                        \
    if (S1) STG(Wt, col0, (t) + 1, 1, 1);                                                  \
    BARX(); LGKM0();                                                                       \
    __builtin_amdgcn_s_setprio(1);                                                         \
    _Pragma("unroll") for (int mi = 0; mi < 8; ++mi) {                                     \
        acc[mi][0] = __builtin_amdgcn_mfma_f32_16x16x32_bf16(af[mi], bq[0], acc[mi][0], 0, 0, 0); \
        acc[mi][1] = __builtin_amdgcn_mfma_f32_16x16x32_bf16(af[mi], bq[1], acc[mi][1], 0, 0, 0); \
    }                                                                                      \
    __builtin_amdgcn_s_setprio(0);                                                         \
    BARX();                                                                                \
    bq[2] = FRAGB(t, 0, 2); bq[3] = FRAGB(t, 0, 3);                                        \
    if (S2) STG(Ap, row0, (t) + 2, 0, 0);                                                  \
    BARX(); LGKM0();                                                                       \
    __builtin_amdgcn_s_setprio(1);                                                         \
    _Pragma("unroll") for (int mi = 0; mi < 8; ++mi) {                                     \
        acc[mi][2] = __builtin_amdgcn_mfma_f32_16x16x32_bf16(af[mi], bq[2], acc[mi][2], 0, 0, 0); \
        acc[mi][3] = __builtin_amdgcn_mfma_f32_16x16x32_bf16(af[mi], bq[3], acc[mi][3], 0, 0, 0); \
    }                                                                                      \
    __builtin_amdgcn_s_setprio(0);                                                         \
    W2; BARX();                                                                            \
    _Pragma("unroll") for (int mi = 0; mi < 8; ++mi) af[mi] = FRAGA(t, 1, mi);             \
    bq[0] = FRAGB(t, 1, 0); bq[1] = FRAGB(t, 1, 1);                                        \
    if (S3) STG(Wt, col0, (t) + 2, 0, 1);                                                  \
    BARX(); LGKM0();                                                                       \
    __builtin_amdgcn_s_setprio(1);                                                         \
    _Pragma("unroll") for (int mi = 0; mi < 8; ++mi) {                                     \
        acc[mi][0] = __builtin_amdgcn_mfma_f32_16x16x32_bf16(af[mi], bq[0], acc[mi][0], 0, 0, 0); \
        acc[mi][1] = __builtin_amdgcn_mfma_f32_16x16x32_bf16(af[mi], bq[1], acc[mi][1], 0, 0, 0); \
    }                                                                                      \
    __builtin_amdgcn_s_setprio(0);                                                         \
    BARX();                                                                                \
    bq[2] = FRAGB(t, 1, 2); bq[3] = FRAGB(t, 1, 3);                                        \
    if (S4) STG(Ap, row0, (t) + 2, 1, 0);                                                  \
    BARX(); LGKM0();                                                                       \
    __builtin_amdgcn_s_setprio(1);                                                         \
    _Pragma("unroll") for (int mi = 0; mi < 8; ++mi) {                                     \
        acc[mi][2] = __builtin_amdgcn_mfma_f32_16x16x32_bf16(af[mi], bq[2], acc[mi][2], 0, 0, 0); \
        acc[mi][3] = __builtin_amdgcn_mfma_f32_16x16x32_bf16(af[mi], bq[3], acc[mi][3], 0, 0, 0); \
    }                                                                                      \
    __builtin_amdgcn_s_setprio(0);                                                         \
    W4; BARX();                                                                            \
} while (0)

__global__ __launch_bounds__(512, 2) void gemm_fused_qkvgate(const short* __restrict__ xnb,
                                                             const short* __restrict__ xb,
                                                             const short* __restrict__ Wt,
                                                             const float* __restrict__ b_qkv,
                                                             const float* __restrict__ b_gate,
                                                             short* __restrict__ qkvb,
                                                             short* __restrict__ sigb,
                                                             float* __restrict__ gmean) {
    __shared__ short ldsbuf[2 * 32768];

    const int bid   = blockIdx.x;
    const int xcd   = bid & 7;
    const int local = bid >> 3;            // 0..31
    const int cx = xcd & 3, ry = xcd >> 2; // 4 col-slabs x 2 row-slabs
    const int bxx = cx * 4 + (local & 3);  // 0..15 col-block
    const int byy = ry * 8 + (local >> 2); // 0..15 row-block
    const int row0 = byy * 256;
    const int col0 = bxx * 256;
    const bool isg = (col0 >= 3 * D);
    const short* Ap = isg ? xb : xnb;

    const int tid  = threadIdx.x;
    const int wid  = tid >> 6;     // 0..7
    const int lane = tid & 63;
    const int wm = wid >> 2;       // 0..1  (row half)
    const int wn = wid & 3;        // 0..3  (col quarter)
    const int fr = lane & 15;
    const int fk = (lane >> 4) * 8;

    const int s_r = lane >> 2;                              // 0..15
    const int s_c = 8 * ((lane & 3) ^ ((lane >> 3) & 3));   // 0,8,16,24 permuted

    f32x4 acc[8][4] = {};

    STG(Ap, row0, 0, 0, 0); MEMFENCE();
    STG(Wt, col0, 0, 0, 1); MEMFENCE();
    STG(Ap, row0, 0, 1, 0); MEMFENCE();
    STG(Wt, col0, 0, 1, 1); MEMFENCE();
    STG(Ap, row0, 1, 0, 0); MEMFENCE();
    STG(Wt, col0, 1, 0, 1); MEMFENCE();
    STG(Ap, row0, 1, 1, 0);
    VMW(10);
    BARX();

    for (int t = 0; t < 14; ++t) GROUP(t, 1, 1, 1, 1, VMW(10), VMW(10));
    GROUP(14, 1, 0, 0, 0, VMW(8), VMW(4));
    GROUP(15, 0, 0, 0, 0, VMW(0), (void)0);

    const int ccol  = lane & 15;
    const int crow4 = (lane >> 4) * 4;
    if (!isg) {
        #pragma unroll
        for (int mi = 0; mi < 8; ++mi) {
            #pragma unroll
            for (int ni = 0; ni < 4; ++ni) {
                int col = col0 + wn * 64 + ni * 16 + ccol;
                float bv = b_qkv[col];
                #pragma unroll
                for (int r = 0; r < 4; ++r) {
                    int row = row0 + wm * 128 + mi * 16 + crow4 + r;
                    qkvb[(size_t)row * (3 * D) + col] = to_bf16(acc[mi][ni][r] + bv);
                }
            }
        }
    } else {
        #pragma unroll
        for (int mi = 0; mi < 8; ++mi) {
            #pragma unroll
            for (int r = 0; r < 4; ++r) {
                int lrow = row0 + wm * 128 + mi * 16 + crow4 + r;
                float psum = 0.0f;
                #pragma unroll
                for (int ni = 0; ni < 4; ++ni) {
                    int col = col0 + wn * 64 + ni * 16 + ccol - 3 * D;   // [0,D)
                    float v = acc[mi][ni][r] + b_gate[col];
                    float sv = 1.0f / (1.0f + __expf(-v));
                    sigb[(size_t)lrow * D + col] = to_bf16(sv);
                    psum += sv;
                }
                psum += __shfl_xor(psum, 1, 64);
                psum += __shfl_xor(psum, 2, 64);
                psum += __shfl_xor(psum, 4, 64);
                psum += __shfl_xor(psum, 8, 64);
                if (ccol == 0) atomicAdd(&gmean[lrow], psum);
            }
        }
    }
}

// ---------------------------------------------------------------------------
// Per-chunk state with INLINE gating on k: Sc[m][d] = sum_t Vt[m]*Kg[t][d],
// zc[d] = sum_t Kg[t][d].  Kt/Vt columns XOR-swizzled at 8-short granularity
// (block t>>3 ^= (d>>3)&7): transpose-scatter writes go 16-way -> uniform
// 2-way (free); reads XOR the group index (b128 vector reads preserved).
// ---------------------------------------------------------------------------
__global__ __launch_bounds__(256) void chunk_state_mfma(const short* __restrict__ qkvb,
                                                        const short* __restrict__ sigb,
                                                        const float* __restrict__ gmean,
                                                        float* __restrict__ Sc,
                                                        float* __restrict__ zc) {
    __shared__ short Kt[DH * LS];   // [d][t-swizzled] gated k
    __shared__ short Vt[DH * LS];   // [m][t-swizzled]
    int idx = blockIdx.x;
    int c = idx & (NC - 1), h = (idx >> 5) & (H - 1), b = idx >> 9;
    size_t bt0 = (size_t)b * T + c * CHUNK;
    const short* kbase = qkvb + bt0 * (3 * D) + D + h * DH;
    const short* vbase = kbase + D;
    const short* sbase = sigb + bt0 * D + h * DH;
    int tid = threadIdx.x;

    #pragma unroll
    for (int l = 0; l < 2; ++l) {
        int i  = tid + l * 256;
        int t  = i >> 3;
        int d8 = (i & 7) * 8;
        int tsw = t ^ ((i & 7) << 3);   // column swizzle: block t>>3 ^= d>>3
        float invm = 1.0f / (gmean[bt0 + t] * (1.0f / D) + 1e-5f);
        bf16x8 kv = *(const bf16x8*)(kbase + (size_t)t * (3 * D) + d8);
        bf16x8 vv = *(const bf16x8*)(vbase + (size_t)t * (3 * D) + d8);
        bf16x8 sg = *(const bf16x8*)(sbase + (size_t)t * D + d8);
        #pragma unroll
        for (int j = 0; j < 8; ++j) {
            float gn = bf2f(sg[j]) * invm;
            Kt[(d8 + j) * LS + tsw] = to_bf16(elu1(bf2f(kv[j]) * gn));
            Vt[(d8 + j) * LS + tsw] = vv[j];
        }
    }
    __syncthreads();

    const int wv = tid >> 6, lane = tid & 63;
    const int fr = lane & 15, quad = lane >> 4;
    const int crow4 = quad * 4, ccol = lane & 15;
    const int mbase = wv * 16;

    const int hV = ((mbase + fr) >> 3) & 7;
    bf16x8 af0 = *(const bf16x8*)&Vt[(mbase + fr) * LS + ((quad ^ hV) << 3)];
    bf16x8 af1 = *(const bf16x8*)&Vt[(mbase + fr) * LS + (((4 + quad) ^ hV) << 3)];

    f32x4 acc[4] = {};
    #pragma unroll
    for (int n = 0; n < 4; ++n) {
        const int hK = ((n * 16 + fr) >> 3) & 7;
        bf16x8 bk0 = *(const bf16x8*)&Kt[(n * 16 + fr) * LS + ((quad ^ hK) << 3)];
        bf16x8 bk1 = *(const bf16x8*)&Kt[(n * 16 + fr) * LS + (((4 + quad) ^ hK) << 3)];
        acc[n] = __builtin_amdgcn_mfma_f32_16x16x32_bf16(af0, bk0, acc[n], 0, 0, 0);
        acc[n] = __builtin_amdgcn_mfma_f32_16x16x32_bf16(af1, bk1, acc[n], 0, 0, 0);
    }

    float* Sd = Sc + (size_t)idx * (DH * DH);
    #pragma unroll
    for (int n = 0; n < 4; ++n)
        #pragma unroll
        for (int r = 0; r < 4; ++r)
            Sd[(mbase + crow4 + r) * DH + n * 16 + ccol] = acc[n][r];

    // zc[d] = sum_t Kt[d][t], all threads: d = tid>>2, 16-wide t-slice per lane
    {
        int d = tid >> 2, p = tid & 3;
        int hz = (d >> 3) & 7;
        bf16x8 k0 = *(const bf16x8*)&Kt[d * LS + (((2 * p) ^ hz) << 3)];
        bf16x8 k1 = *(const bf16x8*)&Kt[d * LS + (((2 * p + 1) ^ hz) << 3)];
        float zs = 0.0f;
        #pragma unroll
        for (int j = 0; j < 8; ++j) zs += bf2f(k0[j]) + bf2f(k1[j]);
        zs += __shfl_xor(zs, 1, 64);
        zs += __shfl_xor(zs, 2, 64);
        if (p == 0) zc[(size_t)idx * DH + d] = zs;
    }
}

// ---------------------------------------------------------------------------
// Exclusive prefix over chunks, register-pipelined (load all 32, then scan).
// Reads fp32 Sc, writes bf16 Spb; z in place.  (R3-verified)
// ---------------------------------------------------------------------------
__global__ __launch_bounds__(256) void chunk_prefix_kernel(const float* __restrict__ S,
                                                           short* __restrict__ Spb,
                                                           float* __restrict__ z) {
    int bh   = blockIdx.x >> 4;
    int part = blockIdx.x & 15;
    int e    = part * 256 + threadIdx.x;
    const float* Sb = S + (size_t)bh * NC * DH * DH;
    short* Pb = Spb + (size_t)bh * NC * DH * DH;
    float v[NC];
    #pragma unroll
    for (int c = 0; c < NC; ++c) v[c] = Sb[(size_t)c * DH * DH + e];
    float acc = 0.0f;
    #pragma unroll
    for (int c = 0; c < NC; ++c) {
        Pb[(size_t)c * DH * DH + e] = to_bf16(acc);
        acc += v[c];
    }
    if (part == 0 && threadIdx.x < DH) {
        float* zb = z + (size_t)bh * NC * DH + threadIdx.x;
        float zv[NC];
        #pragma unroll
        for (int c = 0; c < NC; ++c) zv[c] = zb[(size_t)c * DH];
        float za = 0.0f;
        #pragma unroll
        for (int c = 0; c < NC; ++c) {
            zb[(size_t)c * DH] = za;
            za += zv[c];
        }
    }
}

// ---------------------------------------------------------------------------
// Chunk attention with INLINE gating on q,k. As aliases Ks (dead after scores).
// Vt columns XOR-swizzled like chunk_state (write 16-way -> 2-way free).
// ---------------------------------------------------------------------------
__global__ __launch_bounds__(256) void chunk_attn_mfma(const short* __restrict__ qkvb,
                                                       const short* __restrict__ sigb,
                                                       const float* __restrict__ gmean,
                                                       const short* __restrict__ Spb,
                                                       const float* __restrict__ zc,
                                                       short* __restrict__ attnb) {
    __shared__ short Qs[CHUNK * LS];   // [t][d] gated q
    __shared__ short Ks[CHUNK * LS];   // [s][d] gated k; reused as As[t][s]
    __shared__ short Vt[DH * LS];      // [m][s-swizzled]
    __shared__ short Ss[DH * LS];      // [m][d]  (prefix state, bf16)
    __shared__ float zpL[DH];
    __shared__ float den[CHUNK];
    short* As = Ks;                    // alias: Ks dead after scores

    int idx = blockIdx.x;
    int c = idx & (NC - 1), h = (idx >> 5) & (H - 1), b = idx >> 9;
    size_t bt0 = (size_t)b * T + c * CHUNK;
    const short* qbase = qkvb + bt0 * (3 * D) + h * DH;
    const short* kbase = qbase + D;
    const short* vbase = qbase + 2 * D;
    const short* sbase = sigb + bt0 * D + h * DH;
    const short* spb = Spb + (size_t)idx * (DH * DH);
    int tid = threadIdx.x;

    #pragma unroll
    for (int l = 0; l < 2; ++l) {
        int i  = tid + l * 256;
        int t  = i >> 3;
        int d8 = (i & 7) * 8;
        int tsw = t ^ ((i & 7) << 3);   // column swizzle for Vt
        float invm = 1.0f / (gmean[bt0 + t] * (1.0f / D) + 1e-5f);
        bf16x8 qv = *(const bf16x8*)(qbase + (size_t)t * (3 * D) + d8);
        bf16x8 kv = *(const bf16x8*)(kbase + (size_t)t * (3 * D) + d8);
        bf16x8 vv = *(const bf16x8*)(vbase + (size_t)t * (3 * D) + d8);
        bf16x8 sg = *(const bf16x8*)(sbase + (size_t)t * D + d8);
        bf16x8 qg, kg;
        #pragma unroll
        for (int j = 0; j < 8; ++j) {
            float gn = bf2f(sg[j]) * invm;
            qg[j] = to_bf16(elu1(bf2f(qv[j]) * gn));
            kg[j] = to_bf16(elu1(bf2f(kv[j]) * gn));
            Vt[(d8 + j) * LS + tsw] = vv[j];
        }
        *(bf16x8*)&Qs[t * LS + d8] = qg;
        *(bf16x8*)&Ks[t * LS + d8] = kg;
        *(bf16x8*)&Ss[t * LS + d8] = *(const bf16x8*)(spb + (size_t)i * 8);
    }
    if (tid < DH) zpL[tid] = zc[(size_t)idx * DH + tid];
    __syncthreads();

    const int wv = tid >> 6, lane = tid & 63;
    const int fr = lane & 15, quad = lane >> 4;
    const int fk = quad * 8, crow4 = quad * 4, ccol = lane & 15;
    const int tbase = wv * 16;

    bf16x8 aq0 = *(const bf16x8*)&Qs[(tbase + fr) * LS + fk];
    bf16x8 aq1 = *(const bf16x8*)&Qs[(tbase + fr) * LS + 32 + fk];

    // scores C[t][s] = q_t . k_s
    f32x4 accs[4] = {};
    #pragma unroll
    for (int n = 0; n < 4; ++n) {
        bf16x8 bk0 = *(const bf16x8*)&Ks[(n * 16 + fr) * LS + fk];
        bf16x8 bk1 = *(const bf16x8*)&Ks[(n * 16 + fr) * LS + 32 + fk];
        accs[n] = __builtin_amdgcn_mfma_f32_16x16x32_bf16(aq0, bk0, accs[n], 0, 0, 0);
        accs[n] = __builtin_amdgcn_mfma_f32_16x16x32_bf16(aq1, bk1, accs[n], 0, 0, 0);
    }
    __syncthreads();   // all Ks reads complete before As overwrites it

    float part[4] = {0.f, 0.f, 0.f, 0.f};
    #pragma unroll
    for (int n = 0; n < 4; ++n) {
        #pragma unroll
        for (int r = 0; r < 4; ++r) {
            int tt = tbase + crow4 + r;
            int ss = n * 16 + ccol;
            float v = (ss <= tt) ? accs[n][r] : 0.0f;
            part[r] += v;
            As[tt * LS + ss] = to_bf16(v);
        }
    }
    #pragma unroll
    for (int r = 0; r < 4; ++r) {
        part[r] += __shfl_xor(part[r], 1, 64);
        part[r] += __shfl_xor(part[r], 2, 64);
        part[r] += __shfl_xor(part[r], 4, 64);
        part[r] += __shfl_xor(part[r], 8, 64);
    }
    if (fr == 0) {
        #pragma unroll
        for (int r = 0; r < 4; ++r) den[tbase + crow4 + r] = part[r];
    }
    __syncthreads();

    // den[t] += q_t . zp, all threads: t = tid>>2, 16-wide d-slice per lane
    {
        int t = tid >> 2, p = tid & 3;
        bf16x8 q0 = *(const bf16x8*)&Qs[t * LS + p * 16];
        bf16x8 q1 = *(const bf16x8*)&Qs[t * LS + p * 16 + 8];
        float qz = 0.0f;
        #pragma unroll
        for (int j = 0; j < 8; ++j)
            qz += bf2f(q0[j]) * zpL[p * 16 + j] + bf2f(q1[j]) * zpL[p * 16 + 8 + j];
        qz += __shfl_xor(qz, 1, 64);
        qz += __shfl_xor(qz, 2, 64);
        if (p == 0) den[t] += qz + 1e-5f;
    }

    // out C[t][m] = Q @ Sp + A @ V
    f32x4 acco[4] = {};
    #pragma unroll
    for (int m4 = 0; m4 < 4; ++m4) {
        bf16x8 bs0 = *(const bf16x8*)&Ss[(m4 * 16 + fr) * LS + fk];
        bf16x8 bs1 = *(const bf16x8*)&Ss[(m4 * 16 + fr) * LS + 32 + fk];
        acco[m4] = __builtin_amdgcn_mfma_f32_16x16x32_bf16(aq0, bs0, acco[m4], 0, 0, 0);
        acco[m4] = __builtin_amdgcn_mfma_f32_16x16x32_bf16(aq1, bs1, acco[m4], 0, 0, 0);
    }
    bf16x8 aa0 = *(const bf16x8*)&As[(tbase + fr) * LS + fk];
    bf16x8 aa1 = *(const bf16x8*)&As[(tbase + fr) * LS + 32 + fk];
    #pragma unroll
    for (int m4 = 0; m4 < 4; ++m4) {
        const int hV = ((m4 * 16 + fr) >> 3) & 7;
        bf16x8 bv0 = *(const bf16x8*)&Vt[(m4 * 16 + fr) * LS + ((quad ^ hV) << 3)];
        bf16x8 bv1 = *(const bf16x8*)&Vt[(m4 * 16 + fr) * LS + (((4 + quad) ^ hV) << 3)];
        acco[m4] = __builtin_amdgcn_mfma_f32_16x16x32_bf16(aa0, bv0, acco[m4], 0, 0, 0);
        acco[m4] = __builtin_amdgcn_mfma_f32_16x16x32_bf16(aa1, bv1, acco[m4], 0, 0, 0);
    }
    __syncthreads();

    short* obase = attnb + bt0 * D + h * DH;
    #pragma unroll
    for (int r = 0; r < 4; ++r) {
        int tt = tbase + crow4 + r;
        float rv = 1.0f / den[tt];
        #pragma unroll
        for (int m4 = 0; m4 < 4; ++m4)
            obase[(size_t)tt * D + m4 * 16 + ccol] = to_bf16(acco[m4][r] * rv);
    }
}

// ---------------------------------------------------------------------------
// Proj GEMM, BK=64 + 3-bit XOR LDS swizzle + XCD-rectangle swizzle (R6).
// ---------------------------------------------------------------------------
#define SWZ64(os) ((os) ^ ((((os) >> 6) & 7) << 3))

__global__ __launch_bounds__(256) void gemm_proj64(const short* __restrict__ A,
                                                   const short* __restrict__ Bt,
                                                   const float* __restrict__ bias,
                                                   float* __restrict__ C) {
    constexpr int BK = 64, K = 1024;
    constexpr int N = 1024;
    __shared__ short Als[64 * BK];    // 8 KB
    __shared__ short Bls[128 * BK];   // 16 KB

    const int bid   = blockIdx.x;
    const int xcd   = bid & 7;
    const int local = bid >> 3;            // 0..63
    const int cx = xcd & 3, ry = xcd >> 2; // 4 col-slabs x 2 row-slabs
    const int lx = local & 1, ly = local >> 1;
    const int bxx = cx * 2 + lx;           // 0..7 col-block
    const int byy = ry * 32 + ly;          // 0..63 row-block

    const int tid  = threadIdx.x;
    const int wave = tid >> 6;
    const int lane = tid & 63;
    const int row0 = byy * 64;
    const int col0 = bxx * 128;
    const int wn = wave * 32;

    f32x4 acc[4][2] = {};
    const int fr = lane & 15;
    const int fk = (lane >> 4) * 8;

    for (int k0 = 0; k0 < K; k0 += BK) {
        __syncthreads();
        #pragma unroll
        for (int u = 0; u < 2; ++u) {
            int slot = tid + u * 256;
            int r = slot >> 3, c8 = (slot & 7) ^ (r & 7);
            GLOAD_LDS16(A + (size_t)(row0 + r) * K + k0 + c8 * 8, &Als[slot * 8]);
        }
        #pragma unroll
        for (int u = 0; u < 4; ++u) {
            int slot = tid + u * 256;
            int r = slot >> 3, c8 = (slot & 7) ^ (r & 7);
            GLOAD_LDS16(Bt + (size_t)(col0 + r) * K + k0 + c8 * 8, &Bls[slot * 8]);
        }
        __syncthreads();

        #pragma unroll
        for (int ck = 0; ck < 2; ++ck) {
            bf16x8 af[4], bfr[2];
            #pragma unroll
            for (int i = 0; i < 4; ++i)
                af[i] = *(const bf16x8*)&Als[SWZ64((i * 16 + fr) * BK + ck * 32 + fk)];
            #pragma unroll
            for (int j = 0; j < 2; ++j)
                bfr[j] = *(const bf16x8*)&Bls[SWZ64((wn + j * 16 + fr) * BK + ck * 32 + fk)];
            #pragma unroll
            for (int mi = 0; mi < 4; ++mi)
                #pragma unroll
                for (int ni = 0; ni < 2; ++ni)
                    acc[mi][ni] = __builtin_amdgcn_mfma_f32_16x16x32_bf16(af[mi], bfr[ni], acc[mi][ni], 0, 0, 0);
        }
    }

    const int ccol  = lane & 15;
    const int crow4 = (lane >> 4) * 4;
    #pragma unroll
    for (int mi = 0; mi < 4; ++mi) {
        #pragma unroll
        for (int ni = 0; ni < 2; ++ni) {
            int col = col0 + wn + ni * 16 + ccol;
            float bv = bias[col];
            #pragma unroll
            for (int r = 0; r < 4; ++r) {
                int row = row0 + mi * 16 + crow4 + r;
                C[(size_t)row * N + col] = acc[mi][ni][r] + bv;
            }
        }
    }
}

// ---------------------------------------------------------------------------
extern "C" void kernel_launch(void* const* d_in, const int* in_sizes, int n_in,
                              void* d_out, int out_size, void* d_ws, size_t ws_size,
                              hipStream_t stream) {
    const float* x      = (const float*)d_in[0];
    const float* ln_g   = (const float*)d_in[1];
    const float* ln_b   = (const float*)d_in[2];
    const float* w_qkv  = (const float*)d_in[3];
    const float* b_qkv  = (const float*)d_in[4];
    const float* w_gate = (const float*)d_in[5];
    const float* b_gate = (const float*)d_in[6];
    const float* w_proj = (const float*)d_in[7];
    const float* b_proj = (const float*)d_in[8];
    float* out = (float*)d_out;

    short* xnb   = (short*)d_ws;                       // BT*D bf16 (8 MB)  [dead after GEMM]
    short* xb    = xnb + (size_t)BT * D;               // BT*D bf16 (8 MB)  [dead after GEMM]
    short* wTc   = xb + (size_t)BT * D;                // 4096*1024 bf16 (8 MB) [dead after GEMM]
    short* wTp   = wTc + (size_t)4096 * 1024;          // D*D bf16 (2 MB)
    short* qkvb  = wTp + (size_t)D * D;                // BT*3D bf16 (24 MB)
    short* sigb  = qkvb + (size_t)BT * 3 * D;          // BT*D bf16 (8 MB)
    short* attnb = sigb + (size_t)BT * D;              // BT*D bf16 (8 MB)
    float* zc    = (float*)(attnb + (size_t)BT * D);   // Bb*H*NC*DH fp32 (256 KB)
    float* gmean = zc + (size_t)Bb * H * NC * DH;      // BT fp32 (16 KB)
    float* Sc    = (float*)xnb;                        // Bb*H*NC*DH*DH fp32 (16 MB), aliases xnb+xb
    short* Spb   = wTc;                                // BT*D bf16 (8 MB), aliases wTc

    pre_kernel<<<1024 + 1280, 256, 0, stream>>>(x, ln_g, ln_b, w_qkv, w_gate, w_proj,
                                                xnb, xb, wTc, wTp, gmean);
    gemm_fused_qkvgate<<<256, 512, 0, stream>>>(
        xnb, xb, wTc, b_qkv, b_gate, qkvb, sigb, gmean);
    chunk_state_mfma<<<Bb * H * NC, 256, 0, stream>>>(qkvb, sigb, gmean, Sc, zc);
    chunk_prefix_kernel<<<Bb * H * 16, 256, 0, stream>>>(Sc, Spb, zc);
    chunk_attn_mfma<<<Bb * H * NC, 256, 0, stream>>>(qkvb, sigb, gmean, Spb, zc, attnb);
    gemm_proj64<<<512, 256, 0, stream>>>(attnb, wTp, b_proj, out);
}